// Round 10
// baseline (89.743 us; speedup 1.0000x reference)
//
#include <hip/hip_runtime.h>
#include <hip/hip_bf16.h>
#include <math.h>

// DotProductAttention B=32, L=2048, D=64, fp32 IO, per-batch key-length mask.
// Round 10: k-split flash-decoding on top of the proven round-6 core.
//  - Diagnosis: makespan was pinned by the LONGEST job (32 sequential
//    k-tiles for valid~2048 q-tiles) -> occupancy/pipeline tweaks (r7-r9)
//    couldn't help. Split k-range of batches with valid>1024 into two
//    chunks handled by independent blocks; combine kernel merges partials
//    (log2-domain flash merge). Longest job 32 -> 16 k-tiles.
//  - Tickets: (b, qt, khalf) = 2048; empty chunks skipped. LPT queue.
//  - GRID 1024 = 4 blocks/CU (LDS 25KB). Per-k-tile code identical to r6.
//  - ws guard: if ws_size < ~17.8MB, fall back to no-split (r6 @ GRID 896).

#define BB 32
#define LL 2048
#define DD 64
#define QBLK 64
#define KBLK 64
#define NTICKETS 2048               // 64 groups x 32 q-tiles

typedef __attribute__((ext_vector_type(8))) short bf16x8;
typedef __attribute__((ext_vector_type(4))) float f32x4;

static __device__ __forceinline__ short f2bf(float f) {
    __hip_bfloat16 h = __float2bfloat16(f);
    return *reinterpret_cast<short*>(&h);
}
static __device__ __forceinline__ unsigned pk2(float a, float b) {
    return (unsigned)(unsigned short)f2bf(a) | ((unsigned)(unsigned short)f2bf(b) << 16);
}
static __device__ __forceinline__ float exp2c(float x) {
    return __builtin_amdgcn_exp2f(x);
}
static __device__ __forceinline__ int kswz(int row) { return (row & 7) << 3; }
static __device__ __forceinline__ int vswz(int d)   { return ((d ^ (d >> 2)) & 7) << 3; }
static __device__ __forceinline__ int pswz(int row) { return (((row & 7) ^ (row >> 3)) & 7) << 3; }

static __device__ __forceinline__ int chunk_tiles(int nt, int half, int do_split) {
    if (!do_split) return half ? 0 : nt;
    if (half) { int c = min(nt, 32) - 16; return c > 0 ? c : 0; }
    return min(nt, 16);
}

// ws int region: [0]=ctr, [1..64]=group order (64 groups = (b,half))
__global__ void init_ctr_kernel(const int* __restrict__ vlen, int* __restrict__ ws,
                                int do_split) {
    int t = threadIdx.x;             // 64 threads = 64 groups
    if (t == 0) ws[0] = 0;
    int b = t >> 1, half = t & 1;
    int nt = (vlen[b] + 63) >> 6;
    int w = chunk_tiles(nt, half, do_split);
    int rank = 0;
    for (int g = 0; g < 64; ++g) {
        int gnt = (vlen[g >> 1] + 63) >> 6;
        int gw = chunk_tiles(gnt, g & 1, do_split);
        rank += (gw > w) || (gw == w && g < t);
    }
    ws[1 + rank] = t;
}

__global__ __launch_bounds__(256, 2) void attn_mfma_kernel(
    const float* __restrict__ Q, const float* __restrict__ K,
    const float* __restrict__ V, const int* __restrict__ vlen,
    float* __restrict__ O, int* __restrict__ ws_i,
    float* __restrict__ acc1, float2* __restrict__ ml0, float2* __restrict__ ml1,
    int do_split)
{
    __shared__ __align__(16) short Ks[KBLK * DD];      // [k][d], kswz
    __shared__ __align__(16) short Vt[DD * KBLK];      // [d][k], vswz
    __shared__ __align__(16) short Pl[4][16 * KBLK];   // per-wave [q][k], pswz
    __shared__ int s_tile;

    int* ctr = ws_i;
    const int* order = ws_i + 1;

    const int tid  = threadIdx.x;
    const int wid  = tid >> 6;
    const int lane = tid & 63;
    const int lq   = lane & 15;
    const int lg   = lane >> 4;

    const int vd4 = (tid & 15) * 4;     // V staging: d base
    const int vkr = (tid >> 4) * 4;     // V staging: k base

    const float QSCALE = 0.125f * 1.44269504088896341f;  // 1/sqrt(D) * log2(e)

    float4 kpre[4], vpre[4];

    for (;;) {
        __syncthreads();                 // prev tile fully done before s_tile reuse
        if (tid == 0) s_tile = atomicAdd(ctr, 1);
        __syncthreads();
        const int ticket = s_tile;
        if (ticket >= NTICKETS) break;

        const int g    = order[ticket >> 5];   // LPT: heaviest chunks first
        const int qt   = ticket & 31;
        const int b    = g >> 1;
        const int half = g & 1;
        const int valid = vlen[b];
        const int nt = (valid + 63) >> 6;
        const int c  = chunk_tiles(nt, half, do_split);
        if (c == 0) continue;                 // empty chunk: next ticket
        const int kt0 = half * 16;            // first global k-tile of chunk
        const bool split = do_split && (nt > 16);

        const int qbase = qt * QBLK + wid * 16;

        const float4* Kg4 = reinterpret_cast<const float4*>(K + (size_t)b * LL * DD);
        const float4* Vg4 = reinterpret_cast<const float4*>(V + (size_t)b * LL * DD);

        auto prefetch = [&](int t) {          // t = GLOBAL k-tile index
            const int base4 = t * KBLK * (DD / 4);
            #pragma unroll
            for (int i = 0; i < 4; ++i) kpre[i] = Kg4[base4 + tid + i * 256];
            #pragma unroll
            for (int r = 0; r < 4; ++r) vpre[r] = Vg4[base4 + (vkr + r) * 16 + (tid & 15)];
        };
        auto stage = [&]() {
            #pragma unroll
            for (int i = 0; i < 4; ++i) {
                int idx = tid + i * 256;
                int kr  = idx >> 4;
                int dc  = (idx & 15) * 4;
                float4 kv = kpre[i];
                int e = (kr * 64 + dc) ^ kswz(kr);
                *reinterpret_cast<uint2*>(&Ks[e]) =
                    make_uint2(pk2(kv.x, kv.y), pk2(kv.z, kv.w));
            }
            float4 v0 = vpre[0], v1 = vpre[1], v2 = vpre[2], v3 = vpre[3];
            int e0 = ((vd4 + 0) * 64 + vkr) ^ vswz(vd4 + 0);
            *reinterpret_cast<uint2*>(&Vt[e0]) = make_uint2(pk2(v0.x, v1.x), pk2(v2.x, v3.x));
            int e1 = ((vd4 + 1) * 64 + vkr) ^ vswz(vd4 + 1);
            *reinterpret_cast<uint2*>(&Vt[e1]) = make_uint2(pk2(v0.y, v1.y), pk2(v2.y, v3.y));
            int e2 = ((vd4 + 2) * 64 + vkr) ^ vswz(vd4 + 2);
            *reinterpret_cast<uint2*>(&Vt[e2]) = make_uint2(pk2(v0.z, v1.z), pk2(v2.z, v3.z));
            int e3 = ((vd4 + 3) * 64 + vkr) ^ vswz(vd4 + 3);
            *reinterpret_cast<uint2*>(&Vt[e3]) = make_uint2(pk2(v0.w, v1.w), pk2(v2.w, v3.w));
        };

        // ---- Q B-frags (regs): lane holds Q[qbase+lq][ds*32 + lg*8 .. +7]
        bf16x8 qf[2];
        {
            const float* Qr = Q + ((size_t)b * LL + qbase + lq) * DD;
            #pragma unroll
            for (int ds_ = 0; ds_ < 2; ++ds_) {
                const float4* p4 = reinterpret_cast<const float4*>(Qr + ds_ * 32 + lg * 8);
                float4 a = p4[0], cc = p4[1];
                bf16x8 f;
                f[0] = f2bf(a.x * QSCALE);  f[1] = f2bf(a.y * QSCALE);
                f[2] = f2bf(a.z * QSCALE);  f[3] = f2bf(a.w * QSCALE);
                f[4] = f2bf(cc.x * QSCALE); f[5] = f2bf(cc.y * QSCALE);
                f[6] = f2bf(cc.z * QSCALE); f[7] = f2bf(cc.w * QSCALE);
                qf[ds_] = f;
            }
        }

        f32x4 acc[4];                    // acc[n][r]: q=lg*4+r, d=n*16+lq
        #pragma unroll
        for (int n = 0; n < 4; ++n) acc[n] = (f32x4){0.f, 0.f, 0.f, 0.f};
        float m_ = -1e30f, l_ = 0.f;     // scalars for q = lq

        prefetch(kt0);

        for (int kt = 0; kt < c; ++kt) {
            const int g_kt = kt0 + kt;
            __syncthreads();             // prev k-tile's LDS consumers done

            stage();                     // regs hold tile g_kt
            __syncthreads();

            if (kt + 1 < c) prefetch(g_kt + 1);

            // ---- swapped QK^T: s[t][r] = S[k = g_kt*64+t*16+lg*4+r][q = lq]
            f32x4 s[4];
            #pragma unroll
            for (int t = 0; t < 4; ++t) {
                f32x4 a = (f32x4){0.f, 0.f, 0.f, 0.f};
                const int krow = t * 16 + lq;
                #pragma unroll
                for (int ds_ = 0; ds_ < 2; ++ds_) {
                    int e = (krow * 64 + ds_ * 32 + lg * 8) ^ kswz(krow);
                    bf16x8 kf = *reinterpret_cast<const bf16x8*>(&Ks[e]);
                    a = __builtin_amdgcn_mfma_f32_16x16x32_bf16(kf, qf[ds_], a, 0, 0, 0);
                }
                s[t] = a;
            }

            // ---- mask (last global tile only), in-lane row-max + 2 shfl
            const bool tail = (g_kt == nt - 1) && (valid & (KBLK - 1));
            if (tail) {
                #pragma unroll
                for (int t = 0; t < 4; ++t)
                    #pragma unroll
                    for (int r = 0; r < 4; ++r) {
                        int kg = g_kt * KBLK + t * 16 + lg * 4 + r;
                        if (kg >= valid) s[t][r] = -1e30f;
                    }
            }
            float mx = s[0][0];
            #pragma unroll
            for (int t = 0; t < 4; ++t)
                #pragma unroll
                for (int r = 0; r < 4; ++r) mx = fmaxf(mx, s[t][r]);
            mx = fmaxf(mx, __shfl_xor(mx, 16, 64));
            mx = fmaxf(mx, __shfl_xor(mx, 32, 64));

            // ---- defer-max (T13, log2 domain THR=8)
            if (__any(mx - m_ > 8.0f)) {
                float mnew = fmaxf(m_, mx);
                float corr = exp2c(m_ - mnew);
                m_ = mnew;
                l_ *= corr;
                #pragma unroll
                for (int r = 0; r < 4; ++r) {
                    float cq = __shfl(corr, lg * 4 + r, 64);
                    #pragma unroll
                    for (int n = 0; n < 4; ++n) acc[n][r] *= cq;
                }
            }

            // ---- p = exp2(s - m), in-lane sum + 2 shfl
            float ls = 0.f;
            #pragma unroll
            for (int t = 0; t < 4; ++t)
                #pragma unroll
                for (int r = 0; r < 4; ++r) {
                    float p = exp2c(s[t][r] - m_);
                    s[t][r] = p;
                    ls += p;
                }
            ls += __shfl_xor(ls, 16, 64);
            ls += __shfl_xor(ls, 32, 64);
            l_ += ls;

            // ---- P -> wave-private LDS (bf16, pswz)
            short* Pw = &Pl[wid][0];
            #pragma unroll
            for (int t = 0; t < 4; ++t) {
                int e = (lq * 64 + t * 16 + lg * 4) ^ pswz(lq);
                *reinterpret_cast<uint2*>(&Pw[e]) =
                    make_uint2(pk2(s[t][0], s[t][1]), pk2(s[t][2], s[t][3]));
            }

            // ---- PV: acc[n] += P(16xK) * V(Kx16), per 32-k chunk
            #pragma unroll
            for (int ks_ = 0; ks_ < 2; ++ks_) {
                int pe = (lq * 64 + ks_ * 32 + lg * 8) ^ pswz(lq);
                bf16x8 pf = *reinterpret_cast<const bf16x8*>(&Pw[pe]);
                #pragma unroll
                for (int n = 0; n < 4; ++n) {
                    int drow = n * 16 + lq;
                    int ve = (drow * 64 + ks_ * 32 + lg * 8) ^ vswz(drow);
                    bf16x8 vf = *reinterpret_cast<const bf16x8*>(&Vt[ve]);
                    acc[n] = __builtin_amdgcn_mfma_f32_16x16x32_bf16(pf, vf, acc[n], 0, 0, 0);
                }
            }
        }

        // ---- epilogue
        if (!split) {
            float linv[4];
            #pragma unroll
            for (int r = 0; r < 4; ++r)
                linv[r] = 1.f / __shfl(l_, lg * 4 + r, 64);
            float* Ob = O + ((size_t)b * LL + qbase) * DD;
            #pragma unroll
            for (int n = 0; n < 4; ++n)
                #pragma unroll
                for (int r = 0; r < 4; ++r)
                    Ob[(size_t)(lg * 4 + r) * DD + n * 16 + lq] = acc[n][r] * linv[r];
        } else {
            // raw (unnormalized) partial accumulate + (m,l) per q-row
            float* A = half ? acc1 : O;
            float* Ab = A + ((size_t)b * LL + qbase) * DD;
            #pragma unroll
            for (int n = 0; n < 4; ++n)
                #pragma unroll
                for (int r = 0; r < 4; ++r)
                    Ab[(size_t)(lg * 4 + r) * DD + n * 16 + lq] = acc[n][r];
            float2* ml = half ? ml1 : ml0;
            if (lane < 16)
                ml[(size_t)(b * 32 + qt) * 64 + wid * 16 + lane] = make_float2(m_, l_);
        }
    }
}

// Merge split partials: O = (2^{m0-m} A0 + 2^{m1-m} A1) / (2^{m0-m} l0 + 2^{m1-m} l1)
__global__ __launch_bounds__(256) void combine_kernel(
    float* __restrict__ O, const float* __restrict__ A1,
    const float2* __restrict__ ml0, const float2* __restrict__ ml1,
    const int* __restrict__ vlen)
{
    const int tile = blockIdx.x;          // b*32 + qt
    const int b = tile >> 5, qt = tile & 31;
    const int nt = (vlen[b] + 63) >> 6;
    if (nt <= 16) return;                 // not split: O already final
    const int tid = threadIdx.x;
    const int q  = tid >> 2;              // 0..63
    const int d0 = (tid & 3) * 16;
    float2 p0 = ml0[(size_t)tile * 64 + q];
    float2 p1 = ml1[(size_t)tile * 64 + q];
    float m  = fmaxf(p0.x, p1.x);
    float w0 = exp2c(p0.x - m), w1 = exp2c(p1.x - m);
    float rd = 1.f / (w0 * p0.y + w1 * p1.y);
    size_t base = ((size_t)b * LL + qt * 64 + q) * DD + d0;
    const float4* a0 = reinterpret_cast<const float4*>(O + base);
    const float4* a1 = reinterpret_cast<const float4*>(A1 + base);
    float4* op = reinterpret_cast<float4*>(O + base);
    #pragma unroll
    for (int i = 0; i < 4; ++i) {
        float4 x = a0[i], y = a1[i];
        float4 o;
        o.x = (w0 * x.x + w1 * y.x) * rd;
        o.y = (w0 * x.y + w1 * y.y) * rd;
        o.z = (w0 * x.z + w1 * y.z) * rd;
        o.w = (w0 * x.w + w1 * y.w) * rd;
        op[i] = o;
    }
}

extern "C" void kernel_launch(void* const* d_in, const int* in_sizes, int n_in,
                              void* d_out, int out_size, void* d_ws, size_t ws_size,
                              hipStream_t stream) {
    const float* Q = (const float*)d_in[0];
    const float* K = (const float*)d_in[1];
    const float* V = (const float*)d_in[2];
    const int* vlen = (const int*)d_in[3];
    float* O = (float*)d_out;

    // ws layout: [0..1KB) int ctr + group order; [1KB..) acc1 (16MB), ml0, ml1
    const size_t ACC1_OFF = 1024;
    const size_t ACC1_SZ  = (size_t)BB * LL * DD * sizeof(float);     // 16 MB
    const size_t ML_SZ    = (size_t)BB * 32 * 64 * sizeof(float2);    // 512 KB
    const size_t NEED     = ACC1_OFF + ACC1_SZ + 2 * ML_SZ;
    const int do_split = (ws_size >= NEED) ? 1 : 0;

    int* ws_i = (int*)d_ws;
    char* base = (char*)d_ws;
    float*  acc1 = (float*)(base + ACC1_OFF);
    float2* ml0  = (float2*)(base + ACC1_OFF + ACC1_SZ);
    float2* ml1  = (float2*)(base + ACC1_OFF + ACC1_SZ + ML_SZ);

    init_ctr_kernel<<<1, 64, 0, stream>>>(vlen, ws_i, do_split);

    const int grid = do_split ? 1024 : 896;
    attn_mfma_kernel<<<grid, 256, 0, stream>>>(Q, K, V, vlen, O, ws_i,
                                               acc1, ml0, ml1, do_split);
    if (do_split)
        combine_kernel<<<BB * 32, 256, 0, stream>>>(O, acc1, ml0, ml1, vlen);
}

// Round 11
// 74.375 us; speedup vs baseline: 1.2066x; 1.2066x over previous
//
#include <hip/hip_runtime.h>
#include <hip/hip_bf16.h>
#include <math.h>

// DotProductAttention B=32, L=2048, D=64, fp32 IO, per-batch key-length mask.
// Round 11: r6 core + K/V pre-converted to bf16 swizzled tile images (ws) +
// global_load_lds DMA staging, double-buffered, one barrier per k-tile.
//  - r10 falsified the makespan theory (occupancy up, time up) -> attack
//    per-tile cost: staging was 8 fp32 loads + ~150 cvt VALU + 12 ds_writes
//    per thread per tile, re-done 32x per batch (once per q-tile block).
//  - convert_kv prepass writes each (b,kt) tile's K (kswz) and V (transposed,
//    vswz) images EXACTLY as the LDS wants them; main kernel stages with 4
//    global_load_lds(16B) per thread (linear dest == pre-swizzled source).
//  - Everything else identical to round 6 (71.9us): swapped QK^T, in-lane
//    softmax, defer-max, P pswz layout, LPT queue, GRID 768.

#define BB 32
#define LL 2048
#define DD 64
#define QBLK 64
#define KBLK 64
#define NTILES (BB * (LL / QBLK))   // 1024
#define GRID 768

typedef __attribute__((ext_vector_type(8))) short bf16x8;
typedef __attribute__((ext_vector_type(4))) float f32x4;

static __device__ __forceinline__ short f2bf(float f) {
    __hip_bfloat16 h = __float2bfloat16(f);
    return *reinterpret_cast<short*>(&h);
}
static __device__ __forceinline__ unsigned pk2(float a, float b) {
    return (unsigned)(unsigned short)f2bf(a) | ((unsigned)(unsigned short)f2bf(b) << 16);
}
static __device__ __forceinline__ float exp2c(float x) {
    return __builtin_amdgcn_exp2f(x);
}
static __device__ __forceinline__ int kswz(int row) { return (row & 7) << 3; }
static __device__ __forceinline__ int vswz(int d)   { return ((d ^ (d >> 2)) & 7) << 3; }
static __device__ __forceinline__ int pswz(int row) { return (((row & 7) ^ (row >> 3)) & 7) << 3; }

// 16B global->LDS copy. Builtin path: HW DMA, LDS dst = lbase + lane*16.
// Fallback path: lane does the copy itself (same bytes, more registers).
static __device__ __forceinline__ void cp16(const unsigned short* g,
                                            unsigned short* lbase, int lane) {
#if __has_builtin(__builtin_amdgcn_global_load_lds)
    __builtin_amdgcn_global_load_lds(
        (__attribute__((address_space(1))) void*)g,
        (__attribute__((address_space(3))) void*)lbase, 16, 0, 0);
#else
    *reinterpret_cast<uint4*>(lbase + lane * 8) =
        *reinterpret_cast<const uint4*>(g);
#endif
}

// ws[0] = queue counter; ws[1..32] = batch ids sorted by valid_len desc (LPT)
__global__ void init_ctr_kernel(const int* __restrict__ vlen, int* __restrict__ ws) {
    int t = threadIdx.x;
    if (t == 0) ws[0] = 0;
    if (t < BB) {
        int v = vlen[t];
        int rank = 0;
        for (int j = 0; j < BB; ++j) {
            int vj = vlen[j];
            rank += (vj > v) || (vj == v && j < t);
        }
        ws[1 + rank] = t;
    }
}

// Convert K,V fp32 -> bf16 tile images, laid out byte-for-byte as the LDS
// buffers the main kernel reads (K: [k][d]^kswz; V: [d][k]^vswz).
// Tile (b,kt) image: 4096 shorts K + 4096 shorts V at kv + (b*32+kt)*8192.
__global__ __launch_bounds__(256) void convert_kv_kernel(
    const float* __restrict__ K, const float* __restrict__ V,
    unsigned short* __restrict__ kv)
{
    const int tile = blockIdx.x;         // b*32 + kt
    const int tid  = threadIdx.x;
    const float*  Kt  = K + (size_t)tile * (KBLK * DD);
    const float4* Vg4 = reinterpret_cast<const float4*>(V + (size_t)tile * (KBLK * DD));
    unsigned short* img = kv + (size_t)tile * 8192;

    // K image: linear offset o=gi*8 -> kr=o>>6, dc=(o&63)^kswz(kr)
    #pragma unroll
    for (int g = 0; g < 2; ++g) {
        int gi = tid + g * 256;          // 8-short group 0..511
        int kr = gi >> 3;
        int dc = ((gi & 7) * 8) ^ kswz(kr);
        const float4* src = reinterpret_cast<const float4*>(Kt + kr * DD + dc);
        float4 a = src[0], c = src[1];
        uint4 w;
        w.x = pk2(a.x, a.y); w.y = pk2(a.z, a.w);
        w.z = pk2(c.x, c.y); w.w = pk2(c.z, c.w);
        *reinterpret_cast<uint4*>(img + (size_t)gi * 8) = w;
    }

    // V image: in-thread 4x4 transpose (same pattern as r6 stage)
    unsigned short* img2 = img + 4096;
    const int vd4 = (tid & 15) * 4;
    const int vkr = (tid >> 4) * 4;
    float4 v0 = Vg4[(vkr + 0) * 16 + (tid & 15)];
    float4 v1 = Vg4[(vkr + 1) * 16 + (tid & 15)];
    float4 v2 = Vg4[(vkr + 2) * 16 + (tid & 15)];
    float4 v3 = Vg4[(vkr + 3) * 16 + (tid & 15)];
    int e0 = ((vd4 + 0) * 64 + vkr) ^ vswz(vd4 + 0);
    *reinterpret_cast<uint2*>(img2 + e0) = make_uint2(pk2(v0.x, v1.x), pk2(v2.x, v3.x));
    int e1 = ((vd4 + 1) * 64 + vkr) ^ vswz(vd4 + 1);
    *reinterpret_cast<uint2*>(img2 + e1) = make_uint2(pk2(v0.y, v1.y), pk2(v2.y, v3.y));
    int e2 = ((vd4 + 2) * 64 + vkr) ^ vswz(vd4 + 2);
    *reinterpret_cast<uint2*>(img2 + e2) = make_uint2(pk2(v0.z, v1.z), pk2(v2.z, v3.z));
    int e3 = ((vd4 + 3) * 64 + vkr) ^ vswz(vd4 + 3);
    *reinterpret_cast<uint2*>(img2 + e3) = make_uint2(pk2(v0.w, v1.w), pk2(v2.w, v3.w));
}

__global__ __launch_bounds__(256, 2) void attn_mfma_kernel(
    const float* __restrict__ Q, const int* __restrict__ vlen,
    const unsigned short* __restrict__ kvimg,
    float* __restrict__ O, int* __restrict__ ws)
{
    __shared__ __align__(16) unsigned short Ks[2][KBLK * DD];   // [buf][k][d], kswz
    __shared__ __align__(16) unsigned short Vt[2][KBLK * DD];   // [buf][d][k], vswz
    __shared__ __align__(16) unsigned short Pl[4][16 * KBLK];   // per-wave [q][k], pswz
    __shared__ int s_tile;

    int* ctr = ws;
    const int* order = ws + 1;

    const int tid  = threadIdx.x;
    const int wid  = tid >> 6;
    const int lane = tid & 63;
    const int lq   = lane & 15;
    const int lg   = lane >> 4;

    const float QSCALE = 0.125f * 1.44269504088896341f;  // 1/sqrt(D) * log2(e)

    for (;;) {
        __syncthreads();                 // prev tile fully done before s_tile reuse
        if (tid == 0) s_tile = atomicAdd(ctr, 1);
        __syncthreads();
        const int tile = s_tile;
        if (tile >= NTILES) break;

        const int b     = order[tile >> 5];   // LPT: longest batches first
        const int qt    = tile & 31;
        const int qbase = qt * QBLK + wid * 16;
        const int valid = vlen[b];
        const int ntiles = (valid + KBLK - 1) / KBLK;

        const unsigned short* tbase = kvimg + (size_t)b * (32 * 8192);

        // stage k-tile t into LDS buf via 16B DMA (4 issues/thread)
        auto load_tile = [&](int t, int buf) {
            const unsigned short* tp = tbase + (size_t)t * 8192 + wid * 512 + lane * 8;
            cp16(tp,        &Ks[buf][wid * 512],        lane);
            cp16(tp + 2048, &Ks[buf][2048 + wid * 512], lane);
            cp16(tp + 4096, &Vt[buf][wid * 512],        lane);
            cp16(tp + 6144, &Vt[buf][2048 + wid * 512], lane);
        };

        // ---- Q B-frags (regs): lane holds Q[qbase+lq][ds*32 + lg*8 .. +7]
        bf16x8 qf[2];
        {
            const float* Qr = Q + ((size_t)b * LL + qbase + lq) * DD;
            #pragma unroll
            for (int ds_ = 0; ds_ < 2; ++ds_) {
                const float4* p4 = reinterpret_cast<const float4*>(Qr + ds_ * 32 + lg * 8);
                float4 a = p4[0], c = p4[1];
                bf16x8 f;
                f[0] = f2bf(a.x * QSCALE); f[1] = f2bf(a.y * QSCALE);
                f[2] = f2bf(a.z * QSCALE); f[3] = f2bf(a.w * QSCALE);
                f[4] = f2bf(c.x * QSCALE); f[5] = f2bf(c.y * QSCALE);
                f[6] = f2bf(c.z * QSCALE); f[7] = f2bf(c.w * QSCALE);
                qf[ds_] = f;
            }
        }

        f32x4 acc[4];                    // acc[n][r]: q=lg*4+r, d=n*16+lq
        #pragma unroll
        for (int n = 0; n < 4; ++n) acc[n] = (f32x4){0.f, 0.f, 0.f, 0.f};
        float m_ = -1e30f, l_ = 0.f;     // scalars for q = lq

        load_tile(0, 0);
        __syncthreads();                 // drain DMA: buf0 ready

        for (int kt = 0; kt < ntiles; ++kt) {
            const int cur = kt & 1;

            // issue next tile's DMA; lands during compute, drained by barrier
            if (kt + 1 < ntiles) load_tile(kt + 1, cur ^ 1);

            // ---- swapped QK^T: s[t][r] = S[k = kt*64+t*16+lg*4+r][q = lq]
            const unsigned short* ks = &Ks[cur][0];
            f32x4 s[4];
            #pragma unroll
            for (int t = 0; t < 4; ++t) {
                f32x4 a = (f32x4){0.f, 0.f, 0.f, 0.f};
                const int krow = t * 16 + lq;
                #pragma unroll
                for (int ds_ = 0; ds_ < 2; ++ds_) {
                    int e = (krow * 64 + ds_ * 32 + lg * 8) ^ kswz(krow);
                    bf16x8 kf = *reinterpret_cast<const bf16x8*>(&ks[e]);
                    a = __builtin_amdgcn_mfma_f32_16x16x32_bf16(kf, qf[ds_], a, 0, 0, 0);
                }
                s[t] = a;
            }

            // ---- mask (last partial tile only), in-lane row-max + 2 shfl
            const bool tail = (kt == ntiles - 1) && (valid & (KBLK - 1));
            if (tail) {
                #pragma unroll
                for (int t = 0; t < 4; ++t)
                    #pragma unroll
                    for (int r = 0; r < 4; ++r) {
                        int kg = kt * KBLK + t * 16 + lg * 4 + r;
                        if (kg >= valid) s[t][r] = -1e30f;
                    }
            }
            float mx = s[0][0];
            #pragma unroll
            for (int t = 0; t < 4; ++t)
                #pragma unroll
                for (int r = 0; r < 4; ++r) mx = fmaxf(mx, s[t][r]);
            mx = fmaxf(mx, __shfl_xor(mx, 16, 64));
            mx = fmaxf(mx, __shfl_xor(mx, 32, 64));

            // ---- defer-max (T13, log2 domain THR=8)
            if (__any(mx - m_ > 8.0f)) {
                float mnew = fmaxf(m_, mx);
                float corr = exp2c(m_ - mnew);
                m_ = mnew;
                l_ *= corr;
                #pragma unroll
                for (int r = 0; r < 4; ++r) {
                    float cq = __shfl(corr, lg * 4 + r, 64);
                    #pragma unroll
                    for (int n = 0; n < 4; ++n) acc[n][r] *= cq;
                }
            }

            // ---- p = exp2(s - m), in-lane sum + 2 shfl
            float ls = 0.f;
            #pragma unroll
            for (int t = 0; t < 4; ++t)
                #pragma unroll
                for (int r = 0; r < 4; ++r) {
                    float p = exp2c(s[t][r] - m_);
                    s[t][r] = p;
                    ls += p;
                }
            ls += __shfl_xor(ls, 16, 64);
            ls += __shfl_xor(ls, 32, 64);
            l_ += ls;

            // ---- P -> wave-private LDS (bf16, pswz); no barrier needed
            unsigned short* Pw = &Pl[wid][0];
            #pragma unroll
            for (int t = 0; t < 4; ++t) {
                int e = (lq * 64 + t * 16 + lg * 4) ^ pswz(lq);
                *reinterpret_cast<uint2*>(&Pw[e]) =
                    make_uint2(pk2(s[t][0], s[t][1]), pk2(s[t][2], s[t][3]));
            }

            // ---- PV: acc[n] += P(16xK) * V(Kx16), per 32-k chunk
            const unsigned short* vt = &Vt[cur][0];
            #pragma unroll
            for (int ks_ = 0; ks_ < 2; ++ks_) {
                int pe = (lq * 64 + ks_ * 32 + lg * 8) ^ pswz(lq);
                bf16x8 pf = *reinterpret_cast<const bf16x8*>(&Pw[pe]);
                #pragma unroll
                for (int n = 0; n < 4; ++n) {
                    int drow = n * 16 + lq;
                    int ve = (drow * 64 + ks_ * 32 + lg * 8) ^ vswz(drow);
                    bf16x8 vf = *reinterpret_cast<const bf16x8*>(&vt[ve]);
                    acc[n] = __builtin_amdgcn_mfma_f32_16x16x32_bf16(pf, vf, acc[n], 0, 0, 0);
                }
            }

            __syncthreads();   // buf[cur^1] DMA complete; buf[cur] reads done
        }

        // ---- epilogue: fetch l for q=lg*4+r via shfl, write O
        float linv[4];
        #pragma unroll
        for (int r = 0; r < 4; ++r)
            linv[r] = 1.f / __shfl(l_, lg * 4 + r, 64);
        float* Ob = O + ((size_t)b * LL + qbase) * DD;
        #pragma unroll
        for (int n = 0; n < 4; ++n) {
            #pragma unroll
            for (int r = 0; r < 4; ++r) {
                Ob[(size_t)(lg * 4 + r) * DD + n * 16 + lq] = acc[n][r] * linv[r];
            }
        }
    }
}

extern "C" void kernel_launch(void* const* d_in, const int* in_sizes, int n_in,
                              void* d_out, int out_size, void* d_ws, size_t ws_size,
                              hipStream_t stream) {
    const float* Q = (const float*)d_in[0];
    const float* K = (const float*)d_in[1];
    const float* V = (const float*)d_in[2];
    const int* vlen = (const int*)d_in[3];
    float* O = (float*)d_out;

    // ws layout: [0..1KB) queue (ctr + LPT order); [1KB..) bf16 K/V images
    // (32 batches x 32 tiles x 16KB = 16MB; ws_size >= 17.8MB proven in r10).
    int* ws_i = (int*)d_ws;
    unsigned short* kvimg = (unsigned short*)((char*)d_ws + 1024);

    init_ctr_kernel<<<1, 64, 0, stream>>>(vlen, ws_i);
    convert_kv_kernel<<<BB * (LL / KBLK), 256, 0, stream>>>(K, V, kvimg);
    attn_mfma_kernel<<<GRID, 256, 0, stream>>>(Q, vlen, kvimg, O, ws_i);
}